// Round 2
// baseline (32.202 us; speedup 1.0000x reference)
//
#include <hip/hip_runtime.h>
#include <hip/hip_fp16.h>
#include <math.h>

#define HH 512
#define WW 512
#define NN 10240
#define TILE 16
#define TXN 32              // tiles per row  (512/16)
#define TYN 32
#define CAP 512             // per-tile candidate capacity (expected ~25, max ~50)
#define A_MIN (1.0f/255.0f)
#define A_MAX 0.999f

// ---------------- kernel 1: per-gaussian parameter prep ----------------
// P0 = (cx, cy, a=0.5A, b=B)   P1 = (c=0.5C, op, r, g)   P2b = blue
// Q  = packed f16x4 (cx, cy, rx+pad, ry+pad) conservative bbox for binning
__global__ __launch_bounds__(256) void prep_kernel(
    const float* __restrict__ xyz, const float* __restrict__ chol,
    const float* __restrict__ opac, const float* __restrict__ feat,
    float4* __restrict__ P0, float4* __restrict__ P1,
    float* __restrict__ P2b, uint2* __restrict__ Q) {
  int n = blockIdx.x * 256 + threadIdx.x;
  if (n >= NN) return;
  float mx = tanhf(xyz[2*n+0]);
  float my = tanhf(xyz[2*n+1]);
  float cx = 0.5f * WW * (mx + 1.0f);
  float cy = 0.5f * HH * (my + 1.0f);
  float l1 = chol[3*n+0] + 0.5f;
  float l2 = chol[3*n+1];
  float l3 = chol[3*n+2] + 0.5f;
  float c00 = l1*l1;
  float c01 = l1*l2;
  float c11 = l2*l2 + l3*l3;
  float det = c00*c11 - c01*c01;      // = l1^2 * l3^2 > 0 always
  float inv = 1.0f / det;
  float A = c11 * inv;
  float B = -c01 * inv;
  float C = c00 * inv;
  float op = opac[n];
  // support: alpha = op*exp(-sigma) >= 1/255  =>  sigma <= log(255*op)
  float smax = logf(op * 255.0f);
  float rx = -1000.0f, ry = -1000.0f;   // very negative => never intersects
  if (smax > 0.0f) {
    rx = sqrtf(2.0f * smax * c00) + 1.0f;   // +1 px safety margin
    ry = sqrtf(2.0f * smax * c11) + 1.0f;
  }
  P0[n]  = make_float4(cx, cy, 0.5f * A, B);
  P1[n]  = make_float4(0.5f * C, op, feat[3*n+0], feat[3*n+1]);
  P2b[n] = feat[3*n+2];
  // f16 pack: +0.3 covers center rounding (<=0.25 ulp/2 @512) + radius rounding
  __half2 h0 = __floats2half2_rn(cx, cy);
  __half2 h1 = __floats2half2_rn(rx + 0.3f, ry + 0.3f);
  uint2 q;
  q.x = *(const unsigned int*)&h0;
  q.y = *(const unsigned int*)&h1;
  Q[n] = q;
}

// ---------------- kernel 2: fused bin + render, one block per 16x16 tile ----
__global__ __launch_bounds__(256) void render_kernel(
    const float4* __restrict__ P0, const float4* __restrict__ P1,
    const float* __restrict__ P2b, const uint2* __restrict__ Q,
    float* __restrict__ out) {
  __shared__ float4 sA[CAP];   // cx, cy, a, b
  __shared__ float4 sB[CAP];   // c, op, r, g
  __shared__ float  sC[CAP];   // blue
  __shared__ int s_cnt;

  int tx = blockIdx.x, ty = blockIdx.y;
  int tid = threadIdx.x;
  if (tid == 0) s_cnt = 0;
  __syncthreads();

  // tile pixel-center extents
  float x0c = tx * TILE + 0.5f, x1c = x0c + (TILE - 1);
  float y0c = ty * TILE + 0.5f, y1c = y0c + (TILE - 1);

  // phase 1: scan all gaussians, build LDS candidate list
  for (int i = tid; i < NN; i += 256) {
    uint2 q = Q[i];
    __half2 h0 = *(const __half2*)&q.x;
    __half2 h1 = *(const __half2*)&q.y;
    float cx = __low2float(h0), cy = __high2float(h0);
    float rx = __low2float(h1), ry = __high2float(h1);
    if (cx - rx <= x1c && cx + rx >= x0c &&
        cy - ry <= y1c && cy + ry >= y0c) {
      int k = atomicAdd(&s_cnt, 1);
      if (k < CAP) {
        sA[k] = P0[i];
        sB[k] = P1[i];
        sC[k] = P2b[i];
      }
    }
  }
  __syncthreads();
  int cnt = min(s_cnt, CAP);

  // phase 2: each thread renders one pixel
  int lx = tid & 15;
  int ly = tid >> 4;
  float px = tx * TILE + lx + 0.5f;
  float py = ty * TILE + ly + 0.5f;
  float accR = 0.0f, accG = 0.0f, accB = 0.0f;

  for (int j = 0; j < cnt; ++j) {
    float4 pa = sA[j];            // LDS broadcast — conflict-free
    float4 pb = sB[j];
    float dx = pa.x - px;
    float dy = pa.y - py;
    float sigma = pa.z * dx * dx + pb.x * dy * dy + pa.w * dy * dx;
    float alpha = fminf(A_MAX, pb.y * __expf(-sigma));
    if (sigma >= 0.0f && alpha >= A_MIN) {
      accR += alpha * pb.z;
      accG += alpha * pb.w;
      accB += alpha * sC[j];
    }
  }

  int x = tx * TILE + lx;
  int y = ty * TILE + ly;
  int pix = y * WW + x;
  out[0 * HH * WW + pix] = fminf(fmaxf(accR, 0.0f), 1.0f);
  out[1 * HH * WW + pix] = fminf(fmaxf(accG, 0.0f), 1.0f);
  out[2 * HH * WW + pix] = fminf(fmaxf(accB, 0.0f), 1.0f);
}

// ---------------- launcher ----------------
extern "C" void kernel_launch(void* const* d_in, const int* in_sizes, int n_in,
                              void* d_out, int out_size, void* d_ws, size_t ws_size,
                              hipStream_t stream) {
  const float* xyz  = (const float*)d_in[0];   // (N,2)
  const float* chol = (const float*)d_in[1];   // (N,3)
  const float* opac = (const float*)d_in[2];   // (N,1)
  const float* feat = (const float*)d_in[3];   // (N,3)

  char* ws = (char*)d_ws;
  float4* P0  = (float4*)(ws);
  float4* P1  = (float4*)(ws + (size_t)NN * 16);
  float*  P2b = (float*) (ws + (size_t)NN * 32);
  uint2*  Q   = (uint2*) (ws + (size_t)NN * 36);
  // total ws use: 10240*44 = 450,560 B

  prep_kernel<<<(NN + 255) / 256, 256, 0, stream>>>(xyz, chol, opac, feat, P0, P1, P2b, Q);
  render_kernel<<<dim3(TXN, TYN), 256, 0, stream>>>(P0, P1, P2b, Q, (float*)d_out);
}